// Round 3
// baseline (358.592 us; speedup 1.0000x reference)
//
#include <hip/hip_runtime.h>
#include <hip/hip_bf16.h>

typedef __hip_bfloat16 bf16;
typedef float f32x4 __attribute__((ext_vector_type(4)));

__device__ __forceinline__ float b2f(bf16 x) { return __bfloat162float(x); }

// Inputs proved float32 (R1/R2 of prior session); bf16 path kept as insurance.
template<bool F32>
__device__ __forceinline__ float ld(const void* p, size_t i) {
  if constexpr (F32) return ((const float*)p)[i];
  else return b2f(((const bf16*)p)[i]);
}

template<bool F32>
__device__ __forceinline__ void ld4(const void* p, size_t i, float v[4]) {
  if constexpr (F32) {
    const float4 a = *(const float4*)((const float*)p + i);
    v[0]=a.x; v[1]=a.y; v[2]=a.z; v[3]=a.w;
  } else {
    union { uint2 u; bf16 h[4]; } t;
    t.u = *(const uint2*)((const bf16*)p + i);
    #pragma unroll
    for (int c = 0; c < 4; ++c) v[c] = b2f(t.h[c]);
  }
}

template<bool F32>
__device__ __forceinline__ void ld8(const void* p, size_t i, float v[8]) {
  if constexpr (F32) {
    const float4 a = *(const float4*)((const float*)p + i);
    const float4 b = *(const float4*)((const float*)p + i + 4);
    v[0]=a.x; v[1]=a.y; v[2]=a.z; v[3]=a.w;
    v[4]=b.x; v[5]=b.y; v[6]=b.z; v[7]=b.w;
  } else {
    union { uint4 u; bf16 h[8]; } t;
    t.u = *(const uint4*)((const bf16*)p + i);
    #pragma unroll
    for (int c = 0; c < 8; ++c) v[c] = b2f(t.h[c]);
  }
}

// NT loads: M1-3 are single-use; keep them from evicting W1-3 out of L2/L3.
// (NT *stores* removed: R2 showed 1.6x write amplification, 99->160 MB.)
template<bool F32>
__device__ __forceinline__ void ld8nt(const void* p, size_t i, float v[8]) {
  if constexpr (F32) {
    const f32x4* q = (const f32x4*)((const float*)p + i);
    const f32x4 a = __builtin_nontemporal_load(q);
    const f32x4 b = __builtin_nontemporal_load(q + 1);
    v[0]=a[0]; v[1]=a[1]; v[2]=a[2]; v[3]=a[3];
    v[4]=b[0]; v[5]=b[1]; v[6]=b[2]; v[7]=b[3];
  } else {
    ld8<false>(p, i, v);
  }
}

__device__ __forceinline__ float plast(float Ec, float Ebl) {
  const float Eb0 = (Ebl == 0.f) ? Ec : Ebl;          // bmask logic
  const float Eb  = Eb0 * 0.95f + 0.05f * Ec;         // EMA_SPEED
  const float adv = Ec - Eb;                          // REW_SENS = 1
  const float R   = -adv * rsqrtf(adv*adv + 1e-6f);   // rms_norm size-1 axis
  return (Eb > 0.f) ? (1.f - R) : 0.f;                // plasticity * mask
}

// B=16, N=128, D=64 ; nodes = B*N = 2048
// ws layout (floats):
//   q @0 (131072) | k @131072 | err @262144 | pl @393216
//   mag @524288 (16) | stats @524304 (2) | flag @524306 (1 int)

// ---------------- Kernel 1: q, k, prediction matvecs + state_mag -------------
// Barrier-free: one WAVE per node (512 blocks x 4 independent waves).
// Lane = (jg, cq): jg = lane>>4 owns j-range [jg*16, jg*16+16), cq = lane&15
// owns output columns 4*cq..+3. state broadcast via __shfl; cross-jg reduce
// via shfl_xor(16/32). All W loads are float4 (4 x 256B segments per instr).
template<bool F32>
__device__ __forceinline__ void k1_wave(
    const void* state, const void* W1, const void* W2, const void* W3,
    float* qw, float* kw, float* mag, float* out_pred, int node, int lane)
{
  const int b = node >> 7;
  const float st = ld<F32>(state, (size_t)node*64 + lane);
  // state magnitude (sum |state| over the node's 64 elements)
  float am = fabsf(st);
  #pragma unroll
  for (int s = 32; s; s >>= 1) am += __shfl_xor(am, s, 64);
  if (lane == 0) atomicAdd(&mag[b], am);

  const int jg = lane >> 4, cq = lane & 15;
  const int c0 = cq * 4;
  const size_t nb = (size_t)node * 4096;
  float aq[4] = {0,0,0,0}, ak[4] = {0,0,0,0}, ap[4] = {0,0,0,0};
  #pragma unroll 4
  for (int jj = 0; jj < 16; ++jj) {
    const int j = jg*16 + jj;
    const float sj = __shfl(st, j, 64);
    const size_t o = nb + (size_t)j*64 + c0;
    float wv[4];
    ld4<F32>(W3, o, wv);
    #pragma unroll
    for (int cc = 0; cc < 4; ++cc) aq[cc] += sj * wv[cc];   // q = state . W3
    ld4<F32>(W2, o, wv);
    #pragma unroll
    for (int cc = 0; cc < 4; ++cc) ak[cc] += sj * wv[cc];   // k = state . W2
    ld4<F32>(W1, o, wv);
    #pragma unroll
    for (int cc = 0; cc < 4; ++cc) ap[cc] += sj * wv[cc];   // raw_pred
  }
  // butterfly over jg: afterwards EVERY lane holds the full sum for its cq
  #pragma unroll
  for (int cc = 0; cc < 4; ++cc) {
    aq[cc] += __shfl_xor(aq[cc], 16, 64); aq[cc] += __shfl_xor(aq[cc], 32, 64);
    ak[cc] += __shfl_xor(ak[cc], 16, 64); ak[cc] += __shfl_xor(ak[cc], 32, 64);
    ap[cc] += __shfl_xor(ap[cc], 16, 64); ap[cc] += __shfl_xor(ap[cc], 32, 64);
  }
  if (jg == 0) {
    *(float4*)(qw + (size_t)node*64 + c0) = make_float4(aq[0], aq[1], aq[2], aq[3]);
  } else if (jg == 1) {
    *(float4*)(kw + (size_t)node*64 + c0) = make_float4(ak[0], ak[1], ak[2], ak[3]);
  } else if (jg == 2) {
    float pr[4];
    #pragma unroll
    for (int cc = 0; cc < 4; ++cc) {
      const float raw = ap[cc] - tanhf(ap[cc]) * 0.6f;              // UNTANH
      pr[cc] = tanhf(raw) * 1.8477590650225735f;                    // sqrt(2+sqrt2)
    }
    *(float4*)(out_pred + (size_t)node*64 + c0) = make_float4(pr[0], pr[1], pr[2], pr[3]);
  }
}

__global__ __launch_bounds__(256) void k1_qkpred(
    const void* __restrict__ state,
    const void* __restrict__ W1, const void* __restrict__ W2,
    const void* __restrict__ W3,
    float* __restrict__ qw, float* __restrict__ kw,
    float* __restrict__ mag, float* __restrict__ out_pred,
    int* __restrict__ flagws)
{
  const int tid = threadIdx.x;
  const int w = tid >> 6, lane = tid & 63;
  // dtype detect: every wave samples the SAME 1024 bf16 elements, so all
  // ballots agree without any cross-wave communication.
  bool huge = false;
  for (int i = lane; i < 1024; i += 64) {
    const float x = b2f(((const bf16*)state)[i]);
    if (!(fabsf(x) < 1e5f)) huge = true;   // catches NaN too
  }
  const bool f32 = (__ballot(huge) != 0ull);   // huge-as-bf16 => really float32
  if (blockIdx.x == 0 && tid == 0) *flagws = f32 ? 1 : 0;   // for k2/k3
  const int node = blockIdx.x * 4 + w;
  if (f32) k1_wave<true >(state, W1, W2, W3, qw, kw, mag, out_pred, node, lane);
  else     k1_wave<false>(state, W1, W2, W3, qw, kw, mag, out_pred, node, lane);
}

// ---------------- Kernel 2: attention tile, A_new, target, err, plasticity --
// 256 blocks = 16 batches x 16 tiles of 8 rows. 256 threads: rr = tid>>5 is
// the row within the tile, c = tid&31; each thread owns m = c+32i, i=0..3.
// All reductions are 32-lane shuffles (no barrier trees). k-slice is staged
// in LDS with stride-65 padding => conflict-free strided reads.
template<bool F32>
__device__ __forceinline__ void k2_body(
    const float* qw, const float* kw, const float* predw,
    const void* noiseA, const void* Aold, const void* outp,
    const void* eye, const void* stomach, const void* Ebase,
    float* errw, float* plw, float* stats,
    float* out_target, float* out_A,
    float* s_k, float* s_q, float* s_A)
{
  const int bidx = blockIdx.x;
  const int b = bidx >> 4;
  const int n0 = (bidx & 15) * 8;
  const int tid = threadIdx.x;

  { // stage k slice [128][64] -> LDS [128][65] (padded), q rows [8][64]
    const float* kwb = kw + (size_t)b * 8192;
    #pragma unroll
    for (int it = 0; it < 8; ++it) {
      const int idx = it*256 + tid;          // float4 index, 0..2047
      const int m = idx >> 4, dq = idx & 15;
      const float4 v = *(const float4*)(kwb + (size_t)idx * 4);
      float* dst = &s_k[m*65 + dq*4];
      dst[0] = v.x; dst[1] = v.y; dst[2] = v.z; dst[3] = v.w;
    }
    if (tid < 128) {
      const int rr = tid >> 4, dq = tid & 15;
      *(float4*)&s_q[rr*64 + dq*4] =
          *(const float4*)(qw + ((size_t)(b*128 + n0 + rr))*64 + dq*4);
    }
  }
  __syncthreads();

  const int rr = tid >> 5, c = tid & 31;
  const int n = n0 + rr;
  const size_t node = (size_t)b*128 + n;

  // raw_A[n, m] for m = c + 32*i
  float acc[4] = {0.f, 0.f, 0.f, 0.f};
  {
    const float* qrow = s_q + rr*64;
    #pragma unroll 8
    for (int j = 0; j < 64; ++j) {
      const float qv = qrow[j];
      acc[0] += qv * s_k[(c     )*65 + j];
      acc[1] += qv * s_k[(c + 32)*65 + j];
      acc[2] += qv * s_k[(c + 64)*65 + j];
      acc[3] += qv * s_k[(c + 96)*65 + j];
    }
  }
  float raw[4];
  #pragma unroll
  for (int i = 0; i < 4; ++i)
    raw[i] = acc[i]*0.125f + 1e-5f*ld<F32>(noiseA, node*128 + c + 32*i);

  // row softmax over 128 via 32-lane shuffles (4 values/lane)
  float rmx = fmaxf(fmaxf(raw[0], raw[1]), fmaxf(raw[2], raw[3]));
  #pragma unroll
  for (int s = 16; s >= 1; s >>= 1) rmx = fmaxf(rmx, __shfl_xor(rmx, s, 64));
  float e[4], S = 0.f;
  #pragma unroll
  for (int i = 0; i < 4; ++i) { e[i] = expf(raw[i] - rmx); S += e[i]; }
  #pragma unroll
  for (int s = 16; s >= 1; s >>= 1) S += __shfl_xor(S, s, 64);
  float ek[4], Sk = 0.f;
  #pragma unroll
  for (int i = 0; i < 4; ++i) {
    const float Pd = e[i] / S;
    ek[i] = ((Pd > 0.007751937984496124f) || (raw[i] == rmx)) ? e[i] : 0.f;  // 1/(N+1)
    Sk += ek[i];
  }
  #pragma unroll
  for (int s = 16; s >= 1; s >>= 1) Sk += __shfl_xor(Sk, s, 64);
  #pragma unroll
  for (int i = 0; i < 4; ++i) {
    const int m = c + 32*i;
    const float P = ek[i] / Sk;
    const float An = (n < 2) ? 0.f
                   : 0.99f * ld<F32>(Aold, node*128 + m) + 0.01f * P;
    out_A[node*128 + m] = An;
    s_A[rr*128 + m] = An;
  }
  __syncthreads();

  // target row: each thread owns d = c and d = c+32
  float t0, t1;
  if (n == 0) {
    t0 = ld<F32>(eye, (size_t)b*64 + c);
    t1 = ld<F32>(eye, (size_t)b*64 + c + 32);
  } else if (n == 1) {
    t0 = ld<F32>(stomach, (size_t)b*64 + c);
    t1 = ld<F32>(stomach, (size_t)b*64 + c + 32);
  } else {
    t0 = 0.f; t1 = 0.f;
    const float* arow = s_A + rr*128;
    const size_t ob = (size_t)b * 8192;
    #pragma unroll 4
    for (int m = 0; m < 128; ++m) {
      const float a = arow[m];
      t0 += a * ld<F32>(outp, ob + m*64 + c);
      t1 += a * ld<F32>(outp, ob + m*64 + c + 32);
    }
  }
  out_target[node*64 + c]      = t0;
  out_target[node*64 + c + 32] = t1;
  const float e0 = predw[node*64 + c]      - t0;
  const float e1 = predw[node*64 + c + 32] - t1;
  errw[node*64 + c]      = e0;
  errw[node*64 + c + 32] = e1;

  // E_curr = softmax(err over d=64), then plasticity*mask
  float mx = fmaxf(e0, e1);
  #pragma unroll
  for (int s = 16; s >= 1; s >>= 1) mx = fmaxf(mx, __shfl_xor(mx, s, 64));
  const float x0 = expf(e0 - mx), x1 = expf(e1 - mx);
  float ss = x0 + x1;
  #pragma unroll
  for (int s = 16; s >= 1; s >>= 1) ss += __shfl_xor(ss, s, 64);
  plw[node*64 + c]      = plast(x0/ss, ld<F32>(Ebase, node*64 + c));
  plw[node*64 + c + 32] = plast(x1/ss, ld<F32>(Ebase, node*64 + c + 32));

  // global err stats (for std, ddof=1)
  float se = e0 + e1, sq = e0*e0 + e1*e1;
  #pragma unroll
  for (int s = 16; s >= 1; s >>= 1) { se += __shfl_xor(se, s, 64); sq += __shfl_xor(sq, s, 64); }
  if (c == 0) { atomicAdd(&stats[0], se); atomicAdd(&stats[1], sq); }
}

__global__ __launch_bounds__(256) void k2_attn(
    const int* __restrict__ flag,
    const float* __restrict__ qw, const float* __restrict__ kw,
    const float* __restrict__ predw,
    const void* __restrict__ noiseA, const void* __restrict__ Aold,
    const void* __restrict__ outp,
    const void* __restrict__ eye, const void* __restrict__ stomach,
    const void* __restrict__ Ebase,
    float* __restrict__ errw, float* __restrict__ plw,
    float* __restrict__ stats,
    float* __restrict__ out_target, float* __restrict__ out_A)
{
  __shared__ alignas(16) float s_k[128*65];   // padded: conflict-free strided reads
  __shared__ alignas(16) float s_q[8*64];
  __shared__ alignas(16) float s_A[8*128];
  if (*flag) k2_body<true >(qw,kw,predw,noiseA,Aold,outp,eye,stomach,Ebase,errw,plw,stats,out_target,out_A,s_k,s_q,s_A);
  else       k2_body<false>(qw,kw,predw,noiseA,Aold,outp,eye,stomach,Ebase,errw,plw,stats,out_target,out_A,s_k,s_q,s_A);
}

// ---------------- Kernel 3: grads, momentum, W update + row rms-norm ---------
// Barrier-free, LDS-free: each of the 8 waves redundantly computes the node's
// 64-wide coefficient vectors (err, ns, pe, c, g) in registers via 64-lane
// butterflies (the 5 small loads are L1-hot, issued BEFORE the 12 big loads
// so prologue math runs under vmcnt(12), not vmcnt(0)). Per-column coeffs
// fetched by __shfl. Waves are fully independent -> no barrier convoy.
template<bool F32>
__device__ __forceinline__ void k3_body(
    const float* errw, const float* plw,
    const void* state, const void* n1raw, const void* n2raw,
    const float* mag, const float* stats, const int* stepc,
    const void* W1, const void* W2, const void* W3,
    const void* M1, const void* M2, const void* M3,
    float* oW1, float* oW2, float* oW3)
{
  const int node = blockIdx.x;
  const int b = node >> 7;
  const int tid = threadIdx.x;
  const int lane = tid & 63;
  const int r = tid >> 3;          // output row 0..63
  const int l8 = tid & 7;          // column group: j = l8*8..+7

  // --- small per-lane loads first (index = lane, i.e. vector element) ---
  const size_t sb = (size_t)node*64 + lane;
  const float e_i  = errw[sb];
  const float pl_i = plw[sb];
  const float st_i = ld<F32>(state, sb);
  const float n1_i = ld<F32>(n1raw, sb);
  const float n2_i = ld<F32>(n2raw, sb);
  const float magb = mag[b];
  const float S1 = stats[0], S2 = stats[1];
  const float scv = (float)stepc[0] + 1.f;

  // --- big loads (12 x dwordx4 per thread) ---
  const size_t off = (size_t)node*4096 + (size_t)r*64 + (size_t)l8*8;
  float w1v[8], w2v[8], w3v[8], m1v[8], m2v[8], m3v[8];
  ld8  <F32>(W1, off, w1v); ld8  <F32>(W2, off, w2v); ld8  <F32>(W3, off, w3v);
  ld8nt<F32>(M1, off, m1v); ld8nt<F32>(M2, off, m2v); ld8nt<F32>(M3, off, m3v);

  // --- prologue math (depends only on the small loads) ---
  const float Mn = 131072.f;                           // B*N*D
  const float var = (S2 - S1*S1/Mn) / (Mn - 1.f);      // ddof=1
  const float stdv = sqrtf(fmaxf(var, 0.f));
  const float ns_i = st_i + n1_i / (1.f + magb)
                   + n2_i * stdv * 0.8f;               // NOISE_SCALE
  float e2 = e_i*e_i, q2 = ns_i*ns_i;
  #pragma unroll
  for (int s = 32; s; s >>= 1) { e2 += __shfl_xor(e2, s, 64); q2 += __shfl_xor(q2, s, 64); }
  // rms_norm(lg) factorizes: mean(lg^2) = (sum err^2)(sum ns^2)/4096
  const float c_i  = -ns_i * rsqrtf(e2 * q2 * (1.f/4096.f) + 1e-6f);
  const float pe_i = pl_i * e_i;                       // plasticity*mask*err
  const float center = fmodf(scv * 0.5f, 64.f);        // SPEED
  float dff = fabsf((float)lane - center);
  dff = fminf(dff, 64.f - dff);
  const float g_i = expf(-dff*dff * (1.f/0.020001f));  // 2*WIDTH^2+1e-6

  const float pe = __shfl(pe_i, r, 64);                // row coefficient
  float cj[8], gj[8];
  #pragma unroll
  for (int cc = 0; cc < 8; ++cc) {
    const int j = l8*8 + cc;
    cj[cc] = __shfl(c_i, j, 64);
    gj[cc] = __shfl(g_i, j, 64);
  }

  // --- main update (depends on big loads) ---
  float t1[8], t2[8], t3[8];
  float ss1 = 0.f, ss2 = 0.f, ss3 = 0.f;
  #pragma unroll
  for (int cc = 0; cc < 8; ++cc) {
    const float lgterm = pe * cj[cc];                  // p_i * lg_ij
    const float g = gj[cc];
    const float g1 = lgterm + 0.01f*w3v[cc] - 0.01f*w1v[cc];  // LAT_DECAY, WD
    const float g2 = lgterm + 0.01f*w1v[cc] - 0.01f*w2v[cc];
    const float g3 = lgterm + 0.01f*w2v[cc] - 0.01f*w3v[cc];
    const float v1 = w1v[cc] + 0.0033f*(0.4f*m1v[cc] + 0.6f*g1*g); // LR, MOMENTUM
    const float v2 = w2v[cc] + 0.0033f*(0.4f*m2v[cc] + 0.6f*g2*g);
    const float v3 = w3v[cc] + 0.0033f*(0.4f*m3v[cc] + 0.6f*g3*g);
    t1[cc] = v1; t2[cc] = v2; t3[cc] = v3;
    ss1 += v1*v1; ss2 += v2*v2; ss3 += v3*v3;
  }
  #pragma unroll
  for (int s = 1; s <= 4; s <<= 1) {
    ss1 += __shfl_xor(ss1, s, 64);
    ss2 += __shfl_xor(ss2, s, 64);
    ss3 += __shfl_xor(ss3, s, 64);
  }
  const float r1 = rsqrtf(ss1*(1.f/64.f) + 1e-6f);     // row rms over j
  const float r2 = rsqrtf(ss2*(1.f/64.f) + 1e-6f);
  const float r3 = rsqrtf(ss3*(1.f/64.f) + 1e-6f);
  // regular stores: L2 merges the half-line pairs into full-line writebacks
  *(float4*)(oW1 + off)     = make_float4(t1[0]*r1, t1[1]*r1, t1[2]*r1, t1[3]*r1);
  *(float4*)(oW1 + off + 4) = make_float4(t1[4]*r1, t1[5]*r1, t1[6]*r1, t1[7]*r1);
  *(float4*)(oW2 + off)     = make_float4(t2[0]*r2, t2[1]*r2, t2[2]*r2, t2[3]*r2);
  *(float4*)(oW2 + off + 4) = make_float4(t2[4]*r2, t2[5]*r2, t2[6]*r2, t2[7]*r2);
  *(float4*)(oW3 + off)     = make_float4(t3[0]*r3, t3[1]*r3, t3[2]*r3, t3[3]*r3);
  *(float4*)(oW3 + off + 4) = make_float4(t3[4]*r3, t3[5]*r3, t3[6]*r3, t3[7]*r3);
}

__global__ __launch_bounds__(512) void k3_update(
    const int* __restrict__ flag,
    const float* __restrict__ errw, const float* __restrict__ plw,
    const void* __restrict__ state, const void* __restrict__ n1raw,
    const void* __restrict__ n2raw,
    const float* __restrict__ mag, const float* __restrict__ stats,
    const int* __restrict__ stepc,
    const void* __restrict__ W1, const void* __restrict__ W2,
    const void* __restrict__ W3,
    const void* __restrict__ M1, const void* __restrict__ M2,
    const void* __restrict__ M3,
    float* __restrict__ oW1, float* __restrict__ oW2, float* __restrict__ oW3)
{
  if (*flag) k3_body<true >(errw,plw,state,n1raw,n2raw,mag,stats,stepc,W1,W2,W3,M1,M2,M3,oW1,oW2,oW3);
  else       k3_body<false>(errw,plw,state,n1raw,n2raw,mag,stats,stepc,W1,W2,W3,M1,M2,M3,oW1,oW2,oW3);
}

extern "C" void kernel_launch(void* const* d_in, const int* in_sizes, int n_in,
                              void* d_out, int out_size, void* d_ws, size_t ws_size,
                              hipStream_t stream) {
  const void* eye     = d_in[0];
  const void* stomach = d_in[1];
  const void* state   = d_in[2];
  const void* outp    = d_in[3];
  const void* W1      = d_in[4];
  const void* W2      = d_in[5];
  const void* W3      = d_in[6];
  const void* M1      = d_in[7];
  const void* M2      = d_in[8];
  const void* M3      = d_in[9];
  const void* Ebase   = d_in[10];
  const void* Aold    = d_in[11];
  const void* noiseA  = d_in[12];
  const void* n1raw   = d_in[13];
  const void* n2raw   = d_in[14];
  const int*  stepc   = (const int*)d_in[15];

  float* ws    = (float*)d_ws;
  float* qw    = ws;
  float* kw    = ws + 131072;
  float* errw  = ws + 262144;
  float* plw   = ws + 393216;
  float* mag   = ws + 524288;
  float* stats = ws + 524304;
  int*   flag  = (int*)(ws + 524306);

  float* out        = (float*)d_out;
  float* out_pred   = out;                 // (B,N,D)
  float* out_target = out + 131072;        // (B,N,D)
  float* out_A      = out + 262144;        // (B,N,N)
  float* oW1        = out + 524288;        // (B,N,D,D)
  float* oW2        = out + 8912896;
  float* oW3        = out + 17301504;

  hipMemsetAsync(mag, 0, 18 * sizeof(float), stream);
  k1_qkpred<<<512, 256, 0, stream>>>(state, W1, W2, W3, qw, kw, mag, out_pred, flag);
  k2_attn<<<256, 256, 0, stream>>>(flag, qw, kw, out_pred, noiseA, Aold, outp,
                                   eye, stomach, Ebase, errw, plw, stats,
                                   out_target, out_A);
  k3_update<<<2048, 512, 0, stream>>>(flag, errw, plw, state, n1raw, n2raw, mag, stats,
                                      stepc, W1, W2, W3, M1, M2, M3, oW1, oW2, oW3);
}

// Round 4
// 333.346 us; speedup vs baseline: 1.0757x; 1.0757x over previous
//
#include <hip/hip_runtime.h>
#include <hip/hip_bf16.h>

typedef __hip_bfloat16 bf16;
typedef float f32x4 __attribute__((ext_vector_type(4)));

__device__ __forceinline__ float b2f(bf16 x) { return __bfloat162float(x); }

// Inputs proved float32 (R1/R2 of prior session); bf16 path kept as insurance.
template<bool F32>
__device__ __forceinline__ float ld(const void* p, size_t i) {
  if constexpr (F32) return ((const float*)p)[i];
  else return b2f(((const bf16*)p)[i]);
}

template<bool F32>
__device__ __forceinline__ void ld4(const void* p, size_t i, float v[4]) {
  if constexpr (F32) {
    const float4 a = *(const float4*)((const float*)p + i);
    v[0]=a.x; v[1]=a.y; v[2]=a.z; v[3]=a.w;
  } else {
    union { uint2 u; bf16 h[4]; } t;
    t.u = *(const uint2*)((const bf16*)p + i);
    #pragma unroll
    for (int c = 0; c < 4; ++c) v[c] = b2f(t.h[c]);
  }
}

template<bool F32>
__device__ __forceinline__ void ld8(const void* p, size_t i, float v[8]) {
  if constexpr (F32) {
    const float4 a = *(const float4*)((const float*)p + i);
    const float4 b = *(const float4*)((const float*)p + i + 4);
    v[0]=a.x; v[1]=a.y; v[2]=a.z; v[3]=a.w;
    v[4]=b.x; v[5]=b.y; v[6]=b.z; v[7]=b.w;
  } else {
    union { uint4 u; bf16 h[8]; } t;
    t.u = *(const uint4*)((const bf16*)p + i);
    #pragma unroll
    for (int c = 0; c < 8; ++c) v[c] = b2f(t.h[c]);
  }
}

// NT loads: M1-3 are single-use; keep them from evicting W1-3 out of L2/L3.
// (NT *stores* removed: R2 showed 1.6x write amplification, 99->160 MB.)
template<bool F32>
__device__ __forceinline__ void ld8nt(const void* p, size_t i, float v[8]) {
  if constexpr (F32) {
    const f32x4* q = (const f32x4*)((const float*)p + i);
    const f32x4 a = __builtin_nontemporal_load(q);
    const f32x4 b = __builtin_nontemporal_load(q + 1);
    v[0]=a[0]; v[1]=a[1]; v[2]=a[2]; v[3]=a[3];
    v[4]=b[0]; v[5]=b[1]; v[6]=b[2]; v[7]=b[3];
  } else {
    ld8<false>(p, i, v);
  }
}

__device__ __forceinline__ float plast(float Ec, float Ebl) {
  const float Eb0 = (Ebl == 0.f) ? Ec : Ebl;          // bmask logic
  const float Eb  = Eb0 * 0.95f + 0.05f * Ec;         // EMA_SPEED
  const float adv = Ec - Eb;                          // REW_SENS = 1
  const float R   = -adv * rsqrtf(adv*adv + 1e-6f);   // rms_norm size-1 axis
  return (Eb > 0.f) ? (1.f - R) : 0.f;                // plasticity * mask
}

// B=16, N=128, D=64 ; nodes = B*N = 2048
// ws layout (floats):
//   q @0 | k @131072 | err @262144 | pl @393216
//   magn @524288 (2048, per-node) | mag @526336 (16, per-batch)
//   stats @526352 (2) | flag @526354 (1 int)

// ---------------- Kernel 1: q, k, prediction matvecs + per-node |state| -----
// One wave per (node, matrix): 6144 waves = 1536 blocks x 4. mat-major decode
// (node = wid & 2047, mat = wid >> 11). Lane = (jg, cq): jg = lane>>4 owns
// rows [jg*16, jg*16+16), cq = lane&15 owns cols 4*cq..+3. 16 ld4 per thread
// in two 8-deep batches off one base (row offsets fold to imm offset:) ->
// ~8 loads in flight/thread, 24 waves/CU for latency hiding.
template<bool F32>
__device__ __forceinline__ void k1_wave(
    const void* state, const void* W1, const void* W2, const void* W3,
    float* qw, float* kw, float* magn, float* out_pred,
    int node, int mat, int lane)
{
  const float st = ld<F32>(state, (size_t)node*64 + lane);
  const int jg = lane >> 4, cq = lane & 15;
  const int c0 = cq * 4;
  const size_t nb = (size_t)node*4096 + (size_t)jg*1024 + c0;  // row jg*16, col c0
  const void* W = (mat == 0) ? W3 : (mat == 1) ? W2 : W1;

  float acc[4] = {0.f, 0.f, 0.f, 0.f};
  float buf[8][4];
  #pragma unroll
  for (int jj = 0; jj < 8; ++jj) ld4<F32>(W, nb + (size_t)jj*64, buf[jj]);
  #pragma unroll
  for (int jj = 0; jj < 8; ++jj) {
    const float sj = __shfl(st, jg*16 + jj, 64);
    #pragma unroll
    for (int cc = 0; cc < 4; ++cc) acc[cc] += sj * buf[jj][cc];
  }
  #pragma unroll
  for (int jj = 0; jj < 8; ++jj) ld4<F32>(W, nb + (size_t)(jj + 8)*64, buf[jj]);
  #pragma unroll
  for (int jj = 0; jj < 8; ++jj) {
    const float sj = __shfl(st, jg*16 + 8 + jj, 64);
    #pragma unroll
    for (int cc = 0; cc < 4; ++cc) acc[cc] += sj * buf[jj][cc];
  }
  // butterfly over the 4 jg groups: every lane ends with the full sum for cq
  #pragma unroll
  for (int cc = 0; cc < 4; ++cc) {
    acc[cc] += __shfl_xor(acc[cc], 16, 64);
    acc[cc] += __shfl_xor(acc[cc], 32, 64);
  }

  if (mat == 2) {
    // per-node state magnitude (atomic-free; reduced to mag[b] in k2)
    float am = fabsf(st);
    #pragma unroll
    for (int s = 32; s; s >>= 1) am += __shfl_xor(am, s, 64);
    if (lane == 0) magn[node] = am;
    if (jg == 0) {
      float pr[4];
      #pragma unroll
      for (int cc = 0; cc < 4; ++cc) {
        const float raw = acc[cc] - tanhf(acc[cc]) * 0.6f;          // UNTANH
        pr[cc] = tanhf(raw) * 1.8477590650225735f;                  // sqrt(2+sqrt2)
      }
      *(float4*)(out_pred + (size_t)node*64 + c0) = make_float4(pr[0], pr[1], pr[2], pr[3]);
    }
  } else if (jg == 0) {
    float* dst = (mat == 0) ? qw : kw;
    *(float4*)(dst + (size_t)node*64 + c0) = make_float4(acc[0], acc[1], acc[2], acc[3]);
  }
}

__global__ __launch_bounds__(256) void k1_qkpred(
    const void* __restrict__ state,
    const void* __restrict__ W1, const void* __restrict__ W2,
    const void* __restrict__ W3,
    float* __restrict__ qw, float* __restrict__ kw,
    float* __restrict__ magn, float* __restrict__ out_pred,
    int* __restrict__ flagws, float* __restrict__ stats)
{
  const int tid = threadIdx.x;
  const int w = tid >> 6, lane = tid & 63;
  // dtype detect: every wave samples the SAME 1024 bf16 elements, so all
  // ballots agree without any cross-wave communication.
  bool huge = false;
  for (int i = lane; i < 1024; i += 64) {
    const float x = b2f(((const bf16*)state)[i]);
    if (!(fabsf(x) < 1e5f)) huge = true;   // catches NaN too
  }
  const bool f32 = (__ballot(huge) != 0ull);   // huge-as-bf16 => really float32
  if (blockIdx.x == 0 && tid == 0) {
    *flagws = f32 ? 1 : 0;                 // for k2/k3
    stats[0] = 0.f; stats[1] = 0.f;        // zeroed before k2's atomics (in-stream order)
  }
  const int wid = blockIdx.x * 4 + w;
  const int node = wid & 2047, mat = wid >> 11;
  if (f32) k1_wave<true >(state, W1, W2, W3, qw, kw, magn, out_pred, node, mat, lane);
  else     k1_wave<false>(state, W1, W2, W3, qw, kw, magn, out_pred, node, mat, lane);
}

// ---------------- Kernel 2: attention tile, A_new, target, err, plasticity --
// 256 blocks = 16 batches x 16 tiles of 8 rows. 256 threads: rr = tid>>5 is
// the row within the tile, c = tid&31; each thread owns m = c+32i, i=0..3.
// All reductions are 32-lane shuffles (no barrier trees). k-slice is staged
// in LDS with stride-65 padding => conflict-free strided reads.
// Tile-0 blocks also reduce magn[128] -> mag[b] (single writer, no atomics).
template<bool F32>
__device__ __forceinline__ void k2_body(
    const float* qw, const float* kw, const float* predw,
    const void* noiseA, const void* Aold, const void* outp,
    const void* eye, const void* stomach, const void* Ebase,
    const float* magn, float* mag,
    float* errw, float* plw, float* stats,
    float* out_target, float* out_A,
    float* s_k, float* s_q, float* s_A)
{
  const int bidx = blockIdx.x;
  const int b = bidx >> 4;
  const int n0 = (bidx & 15) * 8;
  const int tid = threadIdx.x;

  if (n0 == 0 && tid < 64) {   // mag[b] = sum of the batch's 128 node mags
    float v = magn[b*128 + tid] + magn[b*128 + 64 + tid];
    #pragma unroll
    for (int s = 32; s; s >>= 1) v += __shfl_xor(v, s, 64);
    if (tid == 0) mag[b] = v;
  }

  { // stage k slice [128][64] -> LDS [128][65] (padded), q rows [8][64]
    const float* kwb = kw + (size_t)b * 8192;
    #pragma unroll
    for (int it = 0; it < 8; ++it) {
      const int idx = it*256 + tid;          // float4 index, 0..2047
      const int m = idx >> 4, dq = idx & 15;
      const float4 v = *(const float4*)(kwb + (size_t)idx * 4);
      float* dst = &s_k[m*65 + dq*4];
      dst[0] = v.x; dst[1] = v.y; dst[2] = v.z; dst[3] = v.w;
    }
    if (tid < 128) {
      const int rr = tid >> 4, dq = tid & 15;
      *(float4*)&s_q[rr*64 + dq*4] =
          *(const float4*)(qw + ((size_t)(b*128 + n0 + rr))*64 + dq*4);
    }
  }
  __syncthreads();

  const int rr = tid >> 5, c = tid & 31;
  const int n = n0 + rr;
  const size_t node = (size_t)b*128 + n;

  // raw_A[n, m] for m = c + 32*i
  float acc[4] = {0.f, 0.f, 0.f, 0.f};
  {
    const float* qrow = s_q + rr*64;
    #pragma unroll 8
    for (int j = 0; j < 64; ++j) {
      const float qv = qrow[j];
      acc[0] += qv * s_k[(c     )*65 + j];
      acc[1] += qv * s_k[(c + 32)*65 + j];
      acc[2] += qv * s_k[(c + 64)*65 + j];
      acc[3] += qv * s_k[(c + 96)*65 + j];
    }
  }
  float raw[4];
  #pragma unroll
  for (int i = 0; i < 4; ++i)
    raw[i] = acc[i]*0.125f + 1e-5f*ld<F32>(noiseA, node*128 + c + 32*i);

  // row softmax over 128 via 32-lane shuffles (4 values/lane)
  float rmx = fmaxf(fmaxf(raw[0], raw[1]), fmaxf(raw[2], raw[3]));
  #pragma unroll
  for (int s = 16; s >= 1; s >>= 1) rmx = fmaxf(rmx, __shfl_xor(rmx, s, 64));
  float e[4], S = 0.f;
  #pragma unroll
  for (int i = 0; i < 4; ++i) { e[i] = expf(raw[i] - rmx); S += e[i]; }
  #pragma unroll
  for (int s = 16; s >= 1; s >>= 1) S += __shfl_xor(S, s, 64);
  float ek[4], Sk = 0.f;
  #pragma unroll
  for (int i = 0; i < 4; ++i) {
    const float Pd = e[i] / S;
    ek[i] = ((Pd > 0.007751937984496124f) || (raw[i] == rmx)) ? e[i] : 0.f;  // 1/(N+1)
    Sk += ek[i];
  }
  #pragma unroll
  for (int s = 16; s >= 1; s >>= 1) Sk += __shfl_xor(Sk, s, 64);
  #pragma unroll
  for (int i = 0; i < 4; ++i) {
    const int m = c + 32*i;
    const float P = ek[i] / Sk;
    const float An = (n < 2) ? 0.f
                   : 0.99f * ld<F32>(Aold, node*128 + m) + 0.01f * P;
    out_A[node*128 + m] = An;
    s_A[rr*128 + m] = An;
  }
  __syncthreads();

  // target row: each thread owns d = c and d = c+32
  float t0, t1;
  if (n == 0) {
    t0 = ld<F32>(eye, (size_t)b*64 + c);
    t1 = ld<F32>(eye, (size_t)b*64 + c + 32);
  } else if (n == 1) {
    t0 = ld<F32>(stomach, (size_t)b*64 + c);
    t1 = ld<F32>(stomach, (size_t)b*64 + c + 32);
  } else {
    t0 = 0.f; t1 = 0.f;
    const float* arow = s_A + rr*128;
    const size_t ob = (size_t)b * 8192;
    #pragma unroll 4
    for (int m = 0; m < 128; ++m) {
      const float a = arow[m];
      t0 += a * ld<F32>(outp, ob + m*64 + c);
      t1 += a * ld<F32>(outp, ob + m*64 + c + 32);
    }
  }
  out_target[node*64 + c]      = t0;
  out_target[node*64 + c + 32] = t1;
  const float e0 = predw[node*64 + c]      - t0;
  const float e1 = predw[node*64 + c + 32] - t1;
  errw[node*64 + c]      = e0;
  errw[node*64 + c + 32] = e1;

  // E_curr = softmax(err over d=64), then plasticity*mask
  float mx = fmaxf(e0, e1);
  #pragma unroll
  for (int s = 16; s >= 1; s >>= 1) mx = fmaxf(mx, __shfl_xor(mx, s, 64));
  const float x0 = expf(e0 - mx), x1 = expf(e1 - mx);
  float ss = x0 + x1;
  #pragma unroll
  for (int s = 16; s >= 1; s >>= 1) ss += __shfl_xor(ss, s, 64);
  plw[node*64 + c]      = plast(x0/ss, ld<F32>(Ebase, node*64 + c));
  plw[node*64 + c + 32] = plast(x1/ss, ld<F32>(Ebase, node*64 + c + 32));

  // global err stats (for std, ddof=1)
  float se = e0 + e1, sq = e0*e0 + e1*e1;
  #pragma unroll
  for (int s = 16; s >= 1; s >>= 1) { se += __shfl_xor(se, s, 64); sq += __shfl_xor(sq, s, 64); }
  if (c == 0) { atomicAdd(&stats[0], se); atomicAdd(&stats[1], sq); }
}

__global__ __launch_bounds__(256) void k2_attn(
    const int* __restrict__ flag,
    const float* __restrict__ qw, const float* __restrict__ kw,
    const float* __restrict__ predw,
    const void* __restrict__ noiseA, const void* __restrict__ Aold,
    const void* __restrict__ outp,
    const void* __restrict__ eye, const void* __restrict__ stomach,
    const void* __restrict__ Ebase,
    const float* __restrict__ magn, float* __restrict__ mag,
    float* __restrict__ errw, float* __restrict__ plw,
    float* __restrict__ stats,
    float* __restrict__ out_target, float* __restrict__ out_A)
{
  __shared__ alignas(16) float s_k[128*65];   // padded: conflict-free strided reads
  __shared__ alignas(16) float s_q[8*64];
  __shared__ alignas(16) float s_A[8*128];
  if (*flag) k2_body<true >(qw,kw,predw,noiseA,Aold,outp,eye,stomach,Ebase,magn,mag,errw,plw,stats,out_target,out_A,s_k,s_q,s_A);
  else       k2_body<false>(qw,kw,predw,noiseA,Aold,outp,eye,stomach,Ebase,magn,mag,errw,plw,stats,out_target,out_A,s_k,s_q,s_A);
}

// ---------------- Kernel 3: grads, momentum, W update + row rms-norm ---------
// Barrier-free, LDS-free: each of the 8 waves redundantly computes the node's
// 64-wide coefficient vectors (err, ns, pe, c, g) in registers via 64-lane
// butterflies (the 5 small loads are L1-hot, issued BEFORE the 12 big loads
// so prologue math runs under vmcnt(12), not vmcnt(0)). Per-column coeffs
// fetched by __shfl. Waves are fully independent -> no barrier convoy.
template<bool F32>
__device__ __forceinline__ void k3_body(
    const float* errw, const float* plw,
    const void* state, const void* n1raw, const void* n2raw,
    const float* mag, const float* stats, const int* stepc,
    const void* W1, const void* W2, const void* W3,
    const void* M1, const void* M2, const void* M3,
    float* oW1, float* oW2, float* oW3)
{
  const int node = blockIdx.x;
  const int b = node >> 7;
  const int tid = threadIdx.x;
  const int lane = tid & 63;
  const int r = tid >> 3;          // output row 0..63
  const int l8 = tid & 7;          // column group: j = l8*8..+7

  // --- small per-lane loads first (index = lane, i.e. vector element) ---
  const size_t sb = (size_t)node*64 + lane;
  const float e_i  = errw[sb];
  const float pl_i = plw[sb];
  const float st_i = ld<F32>(state, sb);
  const float n1_i = ld<F32>(n1raw, sb);
  const float n2_i = ld<F32>(n2raw, sb);
  const float magb = mag[b];
  const float S1 = stats[0], S2 = stats[1];
  const float scv = (float)stepc[0] + 1.f;

  // --- big loads (12 x dwordx4 per thread) ---
  const size_t off = (size_t)node*4096 + (size_t)r*64 + (size_t)l8*8;
  float w1v[8], w2v[8], w3v[8], m1v[8], m2v[8], m3v[8];
  ld8  <F32>(W1, off, w1v); ld8  <F32>(W2, off, w2v); ld8  <F32>(W3, off, w3v);
  ld8nt<F32>(M1, off, m1v); ld8nt<F32>(M2, off, m2v); ld8nt<F32>(M3, off, m3v);

  // --- prologue math (depends only on the small loads) ---
  const float Mn = 131072.f;                           // B*N*D
  const float var = (S2 - S1*S1/Mn) / (Mn - 1.f);      // ddof=1
  const float stdv = sqrtf(fmaxf(var, 0.f));
  const float ns_i = st_i + n1_i / (1.f + magb)
                   + n2_i * stdv * 0.8f;               // NOISE_SCALE
  float e2 = e_i*e_i, q2 = ns_i*ns_i;
  #pragma unroll
  for (int s = 32; s; s >>= 1) { e2 += __shfl_xor(e2, s, 64); q2 += __shfl_xor(q2, s, 64); }
  // rms_norm(lg) factorizes: mean(lg^2) = (sum err^2)(sum ns^2)/4096
  const float c_i  = -ns_i * rsqrtf(e2 * q2 * (1.f/4096.f) + 1e-6f);
  const float pe_i = pl_i * e_i;                       // plasticity*mask*err
  const float center = fmodf(scv * 0.5f, 64.f);        // SPEED
  float dff = fabsf((float)lane - center);
  dff = fminf(dff, 64.f - dff);
  const float g_i = expf(-dff*dff * (1.f/0.020001f));  // 2*WIDTH^2+1e-6

  const float pe = __shfl(pe_i, r, 64);                // row coefficient
  float cj[8], gj[8];
  #pragma unroll
  for (int cc = 0; cc < 8; ++cc) {
    const int j = l8*8 + cc;
    cj[cc] = __shfl(c_i, j, 64);
    gj[cc] = __shfl(g_i, j, 64);
  }

  // --- main update (depends on big loads) ---
  float t1[8], t2[8], t3[8];
  float ss1 = 0.f, ss2 = 0.f, ss3 = 0.f;
  #pragma unroll
  for (int cc = 0; cc < 8; ++cc) {
    const float lgterm = pe * cj[cc];                  // p_i * lg_ij
    const float g = gj[cc];
    const float g1 = lgterm + 0.01f*w3v[cc] - 0.01f*w1v[cc];  // LAT_DECAY, WD
    const float g2 = lgterm + 0.01f*w1v[cc] - 0.01f*w2v[cc];
    const float g3 = lgterm + 0.01f*w2v[cc] - 0.01f*w3v[cc];
    const float v1 = w1v[cc] + 0.0033f*(0.4f*m1v[cc] + 0.6f*g1*g); // LR, MOMENTUM
    const float v2 = w2v[cc] + 0.0033f*(0.4f*m2v[cc] + 0.6f*g2*g);
    const float v3 = w3v[cc] + 0.0033f*(0.4f*m3v[cc] + 0.6f*g3*g);
    t1[cc] = v1; t2[cc] = v2; t3[cc] = v3;
    ss1 += v1*v1; ss2 += v2*v2; ss3 += v3*v3;
  }
  #pragma unroll
  for (int s = 1; s <= 4; s <<= 1) {
    ss1 += __shfl_xor(ss1, s, 64);
    ss2 += __shfl_xor(ss2, s, 64);
    ss3 += __shfl_xor(ss3, s, 64);
  }
  const float r1 = rsqrtf(ss1*(1.f/64.f) + 1e-6f);     // row rms over j
  const float r2 = rsqrtf(ss2*(1.f/64.f) + 1e-6f);
  const float r3 = rsqrtf(ss3*(1.f/64.f) + 1e-6f);
  // regular stores: L2 merges the half-line pairs into full-line writebacks
  *(float4*)(oW1 + off)     = make_float4(t1[0]*r1, t1[1]*r1, t1[2]*r1, t1[3]*r1);
  *(float4*)(oW1 + off + 4) = make_float4(t1[4]*r1, t1[5]*r1, t1[6]*r1, t1[7]*r1);
  *(float4*)(oW2 + off)     = make_float4(t2[0]*r2, t2[1]*r2, t2[2]*r2, t2[3]*r2);
  *(float4*)(oW2 + off + 4) = make_float4(t2[4]*r2, t2[5]*r2, t2[6]*r2, t2[7]*r2);
  *(float4*)(oW3 + off)     = make_float4(t3[0]*r3, t3[1]*r3, t3[2]*r3, t3[3]*r3);
  *(float4*)(oW3 + off + 4) = make_float4(t3[4]*r3, t3[5]*r3, t3[6]*r3, t3[7]*r3);
}

__global__ __launch_bounds__(512) void k3_update(
    const int* __restrict__ flag,
    const float* __restrict__ errw, const float* __restrict__ plw,
    const void* __restrict__ state, const void* __restrict__ n1raw,
    const void* __restrict__ n2raw,
    const float* __restrict__ mag, const float* __restrict__ stats,
    const int* __restrict__ stepc,
    const void* __restrict__ W1, const void* __restrict__ W2,
    const void* __restrict__ W3,
    const void* __restrict__ M1, const void* __restrict__ M2,
    const void* __restrict__ M3,
    float* __restrict__ oW1, float* __restrict__ oW2, float* __restrict__ oW3)
{
  if (*flag) k3_body<true >(errw,plw,state,n1raw,n2raw,mag,stats,stepc,W1,W2,W3,M1,M2,M3,oW1,oW2,oW3);
  else       k3_body<false>(errw,plw,state,n1raw,n2raw,mag,stats,stepc,W1,W2,W3,M1,M2,M3,oW1,oW2,oW3);
}

extern "C" void kernel_launch(void* const* d_in, const int* in_sizes, int n_in,
                              void* d_out, int out_size, void* d_ws, size_t ws_size,
                              hipStream_t stream) {
  const void* eye     = d_in[0];
  const void* stomach = d_in[1];
  const void* state   = d_in[2];
  const void* outp    = d_in[3];
  const void* W1      = d_in[4];
  const void* W2      = d_in[5];
  const void* W3      = d_in[6];
  const void* M1      = d_in[7];
  const void* M2      = d_in[8];
  const void* M3      = d_in[9];
  const void* Ebase   = d_in[10];
  const void* Aold    = d_in[11];
  const void* noiseA  = d_in[12];
  const void* n1raw   = d_in[13];
  const void* n2raw   = d_in[14];
  const int*  stepc   = (const int*)d_in[15];

  float* ws    = (float*)d_ws;
  float* qw    = ws;
  float* kw    = ws + 131072;
  float* errw  = ws + 262144;
  float* plw   = ws + 393216;
  float* magn  = ws + 524288;   // per-node |state| sums (2048)
  float* mag   = ws + 526336;   // per-batch sums (16)
  float* stats = ws + 526352;
  int*   flag  = (int*)(ws + 526354);

  float* out        = (float*)d_out;
  float* out_pred   = out;                 // (B,N,D)
  float* out_target = out + 131072;        // (B,N,D)
  float* out_A      = out + 262144;        // (B,N,N)
  float* oW1        = out + 524288;        // (B,N,D,D)
  float* oW2        = out + 8912896;
  float* oW3        = out + 17301504;

  // no memset: stats zeroed by k1 (precedes k2's atomics in-stream);
  // magn/mag/flag are fully overwritten each iteration.
  k1_qkpred<<<1536, 256, 0, stream>>>(state, W1, W2, W3, qw, kw, magn, out_pred,
                                      flag, stats);
  k2_attn<<<256, 256, 0, stream>>>(flag, qw, kw, out_pred, noiseA, Aold, outp,
                                   eye, stomach, Ebase, magn, mag, errw, plw, stats,
                                   out_target, out_A);
  k3_update<<<2048, 512, 0, stream>>>(flag, errw, plw, state, n1raw, n2raw, mag, stats,
                                      stepc, W1, W2, W3, M1, M2, M3, oW1, oW2, oW3);
}